// Round 6
// baseline (347.983 us; speedup 1.0000x reference)
//
#include <hip/hip_runtime.h>

#define N_COLS 24576
#define ROWS 4096
#define KSEL 64
#define TPB 256
#define PRE_F 2.5f        // static prefilter; 64th-largest of a N(0,1) row ≈ 2.79±0.04
#define CAPG 256          // per-row candidate cap in ws (E[C]=152, σ≈12 → 8.4σ margin)
#define NBINS 2048

#define GRID1 2048
#define F4_TOTAL (ROWS * (N_COLS / 4))        // 25165824
#define ITERS1 (F4_TOTAL / (GRID1 * TPB))     // 48

__device__ __forceinline__ unsigned toSortable(float x) {
    unsigned u = __float_as_uint(x);
    return (u & 0x80000000u) ? ~u : (u | 0x80000000u);
}
__device__ __forceinline__ float fromSortable(unsigned s) {
    unsigned u = (s & 0x80000000u) ? (s & 0x7FFFFFFFu) : ~s;
    return __uint_as_float(u);
}

// ---------------- K0: zero the per-row counters in ws ----------------
extern "C" __global__ void zero_cnt_kernel(unsigned* __restrict__ cnt) {
    int i = blockIdx.x * blockDim.x + threadIdx.x;
    if (i < ROWS) cnt[i] = 0u;
}

// ---- K1: dense grid-stride read of x, push rare candidates to ws ----
extern "C" __global__ void __launch_bounds__(TPB, 8)
collect_kernel(const float* __restrict__ x, unsigned* __restrict__ cnt,
               unsigned long long* __restrict__ cand) {
    const unsigned t0 = blockIdx.x * TPB + threadIdx.x;
    const float4* __restrict__ x4 = (const float4*)x;
    #pragma unroll 4
    for (int j = 0; j < ITERS1; ++j) {
        unsigned f4 = t0 + (unsigned)j * (GRID1 * TPB);   // dense moving front
        float4 v = x4[f4];
        float m = fmaxf(fmaxf(v.x, v.y), fmaxf(v.z, v.w));
        if (m > PRE_F) {
            unsigned row = f4 / 6144u;                    // 6144 float4 per row
            unsigned colbase = (f4 - row * 6144u) * 4u;
            #define CPUSH(comp, e)                                                \
            if (v.comp > PRE_F) {                                                 \
                unsigned p = atomicAdd(&cnt[row], 1u);                            \
                if (p < CAPG) {                                                   \
                    unsigned s = toSortable(v.comp);                              \
                    cand[(size_t)row * CAPG + p] =                                \
                        ((unsigned long long)s << 15) |                           \
                        (unsigned long long)(24575u - (colbase + e));             \
                }                                                                 \
            }
            CPUSH(x, 0) CPUSH(y, 1) CPUSH(z, 2) CPUSH(w, 3)
            #undef CPUSH
        }
    }
}

// ---------------- K2: dense zero-fill of out (write stream) ----------------
extern "C" __global__ void __launch_bounds__(TPB, 8)
fill_zero_kernel(float4* __restrict__ out) {
    const float4 z4 = {0.0f, 0.0f, 0.0f, 0.0f};
    unsigned base = blockIdx.x * TPB + threadIdx.x;
    #pragma unroll 8
    for (int j = 0; j < ITERS1; ++j)
        out[base + (size_t)j * (GRID1 * TPB)] = z4;
}

// ------- K3: per-row rank-select among candidates, sparse scatter -------
extern "C" __global__ void __launch_bounds__(TPB, 8)
select_scatter_kernel(const float* __restrict__ x, const unsigned* __restrict__ cnt,
                      const unsigned long long* __restrict__ cand,
                      float* __restrict__ out) {
    __shared__ unsigned long long lc[CAPG];
    __shared__ unsigned hist[NBINS];
    __shared__ int sh_b1, sh_g, sh_c2;

    const int tid = threadIdx.x;
    const int row = blockIdx.x;
    const int C = (int)cnt[row];

    if (C >= KSEL && C <= CAPG) {
        // fast exact path: everything excluded by prefilter is < every candidate
        if (tid < C) lc[tid] = cand[(size_t)row * CAPG + tid];
        __syncthreads();
        if (tid < C) {
            unsigned long long ki = lc[tid];
            int rank = 0;
            for (int j = 0; j < C; ++j)
                rank += (lc[j] > ki) ? 1 : 0;     // broadcast LDS reads
            if (rank < KSEL) {
                int idx = 24575 - (int)(ki & 0x7FFFULL);
                float v = fromSortable((unsigned)(ki >> 15));
                out[(size_t)row * N_COLS + idx] = fmaxf(v, 0.0f);
            }
        }
        return;
    }

    // ---- exact histogram fallback (not taken for N(0,1) input) ----
    for (int i = tid; i < NBINS; i += TPB) hist[i] = 0u;
    if (tid == 0) sh_c2 = 0;
    __syncthreads();

    const float4* __restrict__ xr = (const float4*)(x + (size_t)row * N_COLS);
    for (int j = 0; j < N_COLS / 4 / TPB; ++j) {
        int f = j * TPB + tid;
        float4 v = xr[f];
        atomicAdd(&hist[toSortable(v.x) >> 21], 1u);
        atomicAdd(&hist[toSortable(v.y) >> 21], 1u);
        atomicAdd(&hist[toSortable(v.z) >> 21], 1u);
        atomicAdd(&hist[toSortable(v.w) >> 21], 1u);
    }
    __syncthreads();

    if (tid < 64) {
        unsigned running = 0;
        for (int c = NBINS / 64 - 1; c >= 0; --c) {
            int bin = c * 64 + tid;
            unsigned bc = hist[bin];
            unsigned incl = bc;
            #pragma unroll
            for (int d = 1; d < 64; d <<= 1) {
                unsigned o = __shfl_up(incl, d, 64);
                if (tid >= d) incl += o;
            }
            unsigned total = __shfl(incl, 63, 64);
            unsigned gt = running + (total - incl);
            bool cond = (gt < KSEL) && (gt + bc >= KSEL);
            unsigned long long msk = __ballot(cond);
            if (msk != 0ULL) {
                if (cond) { sh_b1 = bin; sh_g = (int)gt; }
                break;
            }
            running += total;
        }
    }
    __syncthreads();

    const int b1 = sh_b1;
    const int g  = sh_g;

    for (int j = 0; j < N_COLS / 4 / TPB; ++j) {
        int f = j * TPB + tid;
        float4 v = xr[f];
        #define FPROC(comp, e)                                                    \
        {                                                                         \
            unsigned s = toSortable(v.comp);                                      \
            int b = (int)(s >> 21);                                               \
            if (b > b1) {                                                         \
                out[(size_t)row * N_COLS + f * 4 + e] = fmaxf(v.comp, 0.0f);      \
            } else if (b == b1) {                                                 \
                int p = atomicAdd(&sh_c2, 1);                                     \
                if (p < CAPG) {                                                   \
                    lc[p] = ((unsigned long long)s << 15) |                       \
                            (unsigned long long)(24575 - (f * 4 + e));            \
                }                                                                 \
            }                                                                     \
        }
        FPROC(x, 0) FPROC(y, 1) FPROC(z, 2) FPROC(w, 3)
        #undef FPROC
    }
    __syncthreads();

    int C2 = sh_c2 < CAPG ? sh_c2 : CAPG;
    const int k1 = KSEL - g;
    for (int i = tid; i < C2; i += TPB) {
        unsigned long long ki = lc[i];
        int rank = 0;
        for (int j = 0; j < C2; ++j)
            rank += (lc[j] > ki) ? 1 : 0;
        if (rank < k1) {
            int idx = 24575 - (int)(ki & 0x7FFFULL);
            float v = fromSortable((unsigned)(ki >> 15));
            out[(size_t)row * N_COLS + idx] = fmaxf(v, 0.0f);
        }
    }
}

// -------- fallback (ws too small): round-4 fused kernel, known-correct --------
extern "C" __global__ void __launch_bounds__(TPB, 8)
fused_topk_kernel(const float* __restrict__ x, float* __restrict__ out) {
    __shared__ unsigned long long lc[CAPG * 2];
    __shared__ unsigned hist[NBINS];
    __shared__ int sh_b1, sh_g, sh_c;

    const int tid = threadIdx.x;
    const int row = blockIdx.x;
    const float4* __restrict__ xr = (const float4*)(x + (size_t)row * N_COLS);
    float4* __restrict__ outr = (float4*)(out + (size_t)row * N_COLS);

    if (tid == 0) sh_c = 0;
    __syncthreads();

    const float4 z4 = {0.0f, 0.0f, 0.0f, 0.0f};
    #pragma unroll 6
    for (int j = 0; j < N_COLS / 4 / TPB; ++j) {
        int f = j * TPB + tid;
        float4 v = xr[f];
        outr[f] = z4;
        #define PREF(comp, e)                                                     \
        if (v.comp > PRE_F) {                                                     \
            int p = atomicAdd(&sh_c, 1);                                          \
            if (p < CAPG * 2) {                                                   \
                unsigned s = toSortable(v.comp);                                  \
                lc[p] = ((unsigned long long)s << 15) |                           \
                        (unsigned long long)(24575 - (f * 4 + e));                \
            }                                                                     \
        }
        PREF(x, 0) PREF(y, 1) PREF(z, 2) PREF(w, 3)
        #undef PREF
    }
    __syncthreads();

    int C = sh_c;
    if (C >= KSEL && C <= CAPG * 2) {
        for (int i = tid; i < C; i += TPB) {
            unsigned long long ki = lc[i];
            int rank = 0;
            for (int j = 0; j < C; ++j)
                rank += (lc[j] > ki) ? 1 : 0;
            if (rank < KSEL) {
                int idx = 24575 - (int)(ki & 0x7FFFULL);
                float v = fromSortable((unsigned)(ki >> 15));
                out[(size_t)row * N_COLS + idx] = fmaxf(v, 0.0f);
            }
        }
        return;
    }

    // exact histogram fallback
    for (int i = tid; i < NBINS; i += TPB) hist[i] = 0u;
    if (tid == 0) sh_c = 0;
    __syncthreads();
    for (int j = 0; j < N_COLS / 4 / TPB; ++j) {
        int f = j * TPB + tid;
        float4 v = xr[f];
        atomicAdd(&hist[toSortable(v.x) >> 21], 1u);
        atomicAdd(&hist[toSortable(v.y) >> 21], 1u);
        atomicAdd(&hist[toSortable(v.z) >> 21], 1u);
        atomicAdd(&hist[toSortable(v.w) >> 21], 1u);
    }
    __syncthreads();
    if (tid < 64) {
        unsigned running = 0;
        for (int c = NBINS / 64 - 1; c >= 0; --c) {
            int bin = c * 64 + tid;
            unsigned bc = hist[bin];
            unsigned incl = bc;
            #pragma unroll
            for (int d = 1; d < 64; d <<= 1) {
                unsigned o = __shfl_up(incl, d, 64);
                if (tid >= d) incl += o;
            }
            unsigned total = __shfl(incl, 63, 64);
            unsigned gt = running + (total - incl);
            bool cond = (gt < KSEL) && (gt + bc >= KSEL);
            unsigned long long msk = __ballot(cond);
            if (msk != 0ULL) {
                if (cond) { sh_b1 = bin; sh_g = (int)gt; }
                break;
            }
            running += total;
        }
    }
    __syncthreads();
    const int b1 = sh_b1;
    const int g  = sh_g;
    for (int j = 0; j < N_COLS / 4 / TPB; ++j) {
        int f = j * TPB + tid;
        float4 v = xr[f];
        #define FPROC2(comp, e)                                                   \
        {                                                                         \
            unsigned s = toSortable(v.comp);                                      \
            int b = (int)(s >> 21);                                               \
            if (b > b1) {                                                         \
                out[(size_t)row * N_COLS + f * 4 + e] = fmaxf(v.comp, 0.0f);      \
            } else if (b == b1) {                                                 \
                int p = atomicAdd(&sh_c, 1);                                      \
                if (p < CAPG * 2) {                                               \
                    lc[p] = ((unsigned long long)s << 15) |                       \
                            (unsigned long long)(24575 - (f * 4 + e));            \
                }                                                                 \
            }                                                                     \
        }
        FPROC2(x, 0) FPROC2(y, 1) FPROC2(z, 2) FPROC2(w, 3)
        #undef FPROC2
    }
    __syncthreads();
    int C2 = sh_c < CAPG * 2 ? sh_c : CAPG * 2;
    const int k1 = KSEL - g;
    for (int i = tid; i < C2; i += TPB) {
        unsigned long long ki = lc[i];
        int rank = 0;
        for (int j = 0; j < C2; ++j)
            rank += (lc[j] > ki) ? 1 : 0;
        if (rank < k1) {
            int idx = 24575 - (int)(ki & 0x7FFFULL);
            float v = fromSortable((unsigned)(ki >> 15));
            out[(size_t)row * N_COLS + idx] = fmaxf(v, 0.0f);
        }
    }
}

extern "C" void kernel_launch(void* const* d_in, const int* in_sizes, int n_in,
                              void* d_out, int out_size, void* d_ws, size_t ws_size,
                              hipStream_t stream) {
    const float* x = (const float*)d_in[0];
    float* out = (float*)d_out;

    const size_t cnt_bytes = ROWS * sizeof(unsigned);
    const size_t cand_bytes = (size_t)ROWS * CAPG * sizeof(unsigned long long);

    if (ws_size >= cnt_bytes + cand_bytes) {
        unsigned* cnt = (unsigned*)d_ws;
        unsigned long long* cand = (unsigned long long*)((char*)d_ws + cnt_bytes);
        zero_cnt_kernel<<<(ROWS + TPB - 1) / TPB, TPB, 0, stream>>>(cnt);
        collect_kernel<<<GRID1, TPB, 0, stream>>>(x, cnt, cand);
        fill_zero_kernel<<<GRID1, TPB, 0, stream>>>((float4*)out);
        select_scatter_kernel<<<ROWS, TPB, 0, stream>>>(x, cnt, cand, out);
    } else {
        fused_topk_kernel<<<ROWS, TPB, 0, stream>>>(x, out);
    }
}

// Round 7
// 283.591 us; speedup vs baseline: 1.2271x; 1.2271x over previous
//
#include <hip/hip_runtime.h>

#define N_COLS 24576
#define ROWS 4096
#define KSEL 64
#define TPB 256
#define PRE_F 2.5f          // static prefilter; 64th-largest of a N(0,1) row ≈ 2.79±0.04
#define CAPB 1024           // per-block LDS candidate cap (E≈305, σ≈17.5 → 40σ)
#define CAPG 256            // per-row candidate cap (E≈152, σ≈12.3 → 8σ)
#define GCAP (768 * 1024)   // global candidate list cap (E≈625K, huge margin)
#define NBINS 2048
#define CAPF 512            // fallback boundary-bin cap

#define GRID1 2048
#define F4_TOTAL (ROWS * (N_COLS / 4))        // 25165824
#define ITERS1 (F4_TOTAL / (GRID1 * TPB))     // 48

// ws layout (bytes): [0..8) hdr {total, overflow_flag}; [8..16392) cnt2[4096];
// [32768 .. +6MB) gcand[GCAP]; then rowcand[ROWS*CAPG]
#define GCAND_OFF 32768
#define WS_NEED (GCAND_OFF + (size_t)GCAP * 8 + (size_t)ROWS * CAPG * 8)

__device__ __forceinline__ unsigned toSortable(float x) {
    unsigned u = __float_as_uint(x);
    return (u & 0x80000000u) ? ~u : (u | 0x80000000u);
}
__device__ __forceinline__ float fromSortable(unsigned s) {
    unsigned u = (s & 0x80000000u) ? (s & 0x7FFFFFFFu) : ~s;
    return __uint_as_float(u);
}

// ---------------- K0: zero hdr + per-row counters ----------------
extern "C" __global__ void zero_hdr_kernel(unsigned* __restrict__ hdr) {
    int i = blockIdx.x * blockDim.x + threadIdx.x;
    if (i < ROWS + 2) hdr[i] = 0u;
}

// ---- K1: dense grid-stride read; block-local LDS list; one reservation ----
extern "C" __global__ void __launch_bounds__(TPB, 8)
collect_kernel(const float* __restrict__ x, unsigned* __restrict__ hdr,
               unsigned long long* __restrict__ gcand) {
    __shared__ unsigned long long blist[CAPB];
    __shared__ unsigned bcnt;
    __shared__ unsigned sbase;

    if (threadIdx.x == 0) bcnt = 0u;
    __syncthreads();

    const unsigned t0 = blockIdx.x * TPB + threadIdx.x;
    const float4* __restrict__ x4 = (const float4*)x;

    #pragma unroll 4
    for (int j = 0; j < ITERS1; ++j) {
        unsigned f4 = t0 + (unsigned)j * (GRID1 * TPB);   // dense moving front
        float4 v = x4[f4];
        if (fmaxf(fmaxf(v.x, v.y), fmaxf(v.z, v.w)) > PRE_F) {  // rare (~2.4%)
            unsigned row = f4 / 6144u;                    // 6144 float4 per row
            unsigned cb = f4 * 4u - row * 24576u;         // col base
            #define CPUSH(comp, e)                                                \
            if (v.comp > PRE_F) {                                                 \
                unsigned p = atomicAdd(&bcnt, 1u);        /* LDS atomic, cheap */ \
                if (p < CAPB) {                                                   \
                    blist[p] = ((unsigned long long)toSortable(v.comp) << 27) |   \
                               ((unsigned long long)row << 15) |                  \
                               (unsigned long long)(24575u - (cb + e));           \
                }                                                                 \
            }
            CPUSH(x, 0) CPUSH(y, 1) CPUSH(z, 2) CPUSH(w, 3)
            #undef CPUSH
        }
    }
    __syncthreads();

    unsigned n = bcnt < CAPB ? bcnt : CAPB;
    if (threadIdx.x == 0) {
        unsigned base = atomicAdd(&hdr[0], n);            // ONE global atomic/block
        sbase = base;
        if (bcnt > CAPB || base + n > GCAP) atomicOr(&hdr[1], 1u);
    }
    __syncthreads();
    const unsigned base = sbase;
    for (unsigned i = threadIdx.x; i < n; i += TPB) {
        unsigned gi = base + i;
        if (gi < GCAP) gcand[gi] = blist[i];              // plain coalesced stores
    }
}

// ---------------- K2: dense zero-fill of out (write stream) ----------------
extern "C" __global__ void __launch_bounds__(TPB, 8)
fill_zero_kernel(float4* __restrict__ out) {
    const float4 z4 = {0.0f, 0.0f, 0.0f, 0.0f};
    unsigned base = blockIdx.x * TPB + threadIdx.x;
    #pragma unroll 8
    for (int j = 0; j < ITERS1; ++j)
        out[base + (size_t)j * (GRID1 * TPB)] = z4;
}

// ---- K2.5: bin global candidate list into per-row lists (~5 MB pass) ----
extern "C" __global__ void __launch_bounds__(TPB, 8)
bin_kernel(unsigned* __restrict__ hdr, const unsigned long long* __restrict__ gcand,
           unsigned long long* __restrict__ rowcand) {
    unsigned N = hdr[0];
    if (N > GCAP) N = GCAP;
    unsigned* cnt2 = hdr + 2;
    for (unsigned i = blockIdx.x * TPB + threadIdx.x; i < N; i += gridDim.x * TPB) {
        unsigned long long k = gcand[i];
        unsigned row = (unsigned)(k >> 15) & 0xFFFu;
        unsigned p = atomicAdd(&cnt2[row], 1u);
        if (p < CAPG) rowcand[(size_t)row * CAPG + p] = k;
    }
}

// ------- K3: per-row rank-select among candidates, sparse scatter -------
extern "C" __global__ void __launch_bounds__(TPB, 8)
select_scatter_kernel(const float* __restrict__ x, const unsigned* __restrict__ hdr,
                      const unsigned long long* __restrict__ rowcand,
                      float* __restrict__ out) {
    __shared__ unsigned long long lc[CAPF];
    __shared__ unsigned hist[NBINS];
    __shared__ int sh_b1, sh_g, sh_c2;

    const int tid = threadIdx.x;
    const int row = blockIdx.x;
    const int C = (int)hdr[2 + row];
    const unsigned overflow = hdr[1];

    if (!overflow && C >= KSEL && C <= CAPG) {
        // fast exact path: everything excluded by prefilter is < every candidate.
        // Entries of one row share the row bits, so raw u64 compare ==
        // (value desc, index asc) — jax.lax.top_k's tie-break.
        if (tid < C) lc[tid] = rowcand[(size_t)row * CAPG + tid];
        __syncthreads();
        if (tid < C) {
            unsigned long long ki = lc[tid];
            int rank = 0;
            for (int j = 0; j < C; ++j)
                rank += (lc[j] > ki) ? 1 : 0;      // broadcast LDS reads
            if (rank < KSEL) {
                int idx = 24575 - (int)(ki & 0x7FFFULL);
                float v = fromSortable((unsigned)(ki >> 27));
                out[(size_t)row * N_COLS + idx] = fmaxf(v, 0.0f);
            }
        }
        return;
    }

    // ---- exact histogram fallback (not taken for N(0,1) input) ----
    for (int i = tid; i < NBINS; i += TPB) hist[i] = 0u;
    if (tid == 0) sh_c2 = 0;
    __syncthreads();

    const float4* __restrict__ xr = (const float4*)(x + (size_t)row * N_COLS);
    for (int j = 0; j < N_COLS / 4 / TPB; ++j) {
        int f = j * TPB + tid;
        float4 v = xr[f];
        atomicAdd(&hist[toSortable(v.x) >> 21], 1u);
        atomicAdd(&hist[toSortable(v.y) >> 21], 1u);
        atomicAdd(&hist[toSortable(v.z) >> 21], 1u);
        atomicAdd(&hist[toSortable(v.w) >> 21], 1u);
    }
    __syncthreads();

    if (tid < 64) {
        unsigned running = 0;
        for (int c = NBINS / 64 - 1; c >= 0; --c) {
            int bin = c * 64 + tid;
            unsigned bc = hist[bin];
            unsigned incl = bc;
            #pragma unroll
            for (int d = 1; d < 64; d <<= 1) {
                unsigned o = __shfl_up(incl, d, 64);
                if (tid >= d) incl += o;
            }
            unsigned total = __shfl(incl, 63, 64);
            unsigned gt = running + (total - incl);
            bool cond = (gt < KSEL) && (gt + bc >= KSEL);
            unsigned long long msk = __ballot(cond);
            if (msk != 0ULL) {
                if (cond) { sh_b1 = bin; sh_g = (int)gt; }
                break;
            }
            running += total;
        }
    }
    __syncthreads();

    const int b1 = sh_b1;
    const int g  = sh_g;

    for (int j = 0; j < N_COLS / 4 / TPB; ++j) {
        int f = j * TPB + tid;
        float4 v = xr[f];
        #define FPROC(comp, e)                                                    \
        {                                                                         \
            unsigned s = toSortable(v.comp);                                      \
            int b = (int)(s >> 21);                                               \
            if (b > b1) {                                                         \
                out[(size_t)row * N_COLS + f * 4 + e] = fmaxf(v.comp, 0.0f);      \
            } else if (b == b1) {                                                 \
                int p = atomicAdd(&sh_c2, 1);                                     \
                if (p < CAPF) {                                                   \
                    lc[p] = ((unsigned long long)s << 15) |                       \
                            (unsigned long long)(24575 - (f * 4 + e));            \
                }                                                                 \
            }                                                                     \
        }
        FPROC(x, 0) FPROC(y, 1) FPROC(z, 2) FPROC(w, 3)
        #undef FPROC
    }
    __syncthreads();

    int C2 = sh_c2 < CAPF ? sh_c2 : CAPF;
    const int k1 = KSEL - g;
    for (int i = tid; i < C2; i += TPB) {
        unsigned long long ki = lc[i];
        int rank = 0;
        for (int j = 0; j < C2; ++j)
            rank += (lc[j] > ki) ? 1 : 0;
        if (rank < k1) {
            int idx = 24575 - (int)(ki & 0x7FFFULL);
            float v = fromSortable((unsigned)(ki >> 15));
            out[(size_t)row * N_COLS + idx] = fmaxf(v, 0.0f);
        }
    }
}

// -------- fallback (ws too small): round-4 fused kernel, known-correct --------
extern "C" __global__ void __launch_bounds__(TPB, 8)
fused_topk_kernel(const float* __restrict__ x, float* __restrict__ out) {
    __shared__ unsigned long long lc[CAPF];
    __shared__ unsigned hist[NBINS];
    __shared__ int sh_b1, sh_g, sh_c;

    const int tid = threadIdx.x;
    const int row = blockIdx.x;
    const float4* __restrict__ xr = (const float4*)(x + (size_t)row * N_COLS);
    float4* __restrict__ outr = (float4*)(out + (size_t)row * N_COLS);

    if (tid == 0) sh_c = 0;
    __syncthreads();

    const float4 z4 = {0.0f, 0.0f, 0.0f, 0.0f};
    #pragma unroll 6
    for (int j = 0; j < N_COLS / 4 / TPB; ++j) {
        int f = j * TPB + tid;
        float4 v = xr[f];
        outr[f] = z4;
        #define PREF(comp, e)                                                     \
        if (v.comp > PRE_F) {                                                     \
            int p = atomicAdd(&sh_c, 1);                                          \
            if (p < CAPF) {                                                       \
                unsigned s = toSortable(v.comp);                                  \
                lc[p] = ((unsigned long long)s << 15) |                           \
                        (unsigned long long)(24575 - (f * 4 + e));                \
            }                                                                     \
        }
        PREF(x, 0) PREF(y, 1) PREF(z, 2) PREF(w, 3)
        #undef PREF
    }
    __syncthreads();

    int C = sh_c;
    if (C >= KSEL && C <= CAPF) {
        for (int i = tid; i < C; i += TPB) {
            unsigned long long ki = lc[i];
            int rank = 0;
            for (int j = 0; j < C; ++j)
                rank += (lc[j] > ki) ? 1 : 0;
            if (rank < KSEL) {
                int idx = 24575 - (int)(ki & 0x7FFFULL);
                float v = fromSortable((unsigned)(ki >> 15));
                out[(size_t)row * N_COLS + idx] = fmaxf(v, 0.0f);
            }
        }
        return;
    }

    for (int i = tid; i < NBINS; i += TPB) hist[i] = 0u;
    if (tid == 0) sh_c = 0;
    __syncthreads();
    for (int j = 0; j < N_COLS / 4 / TPB; ++j) {
        int f = j * TPB + tid;
        float4 v = xr[f];
        atomicAdd(&hist[toSortable(v.x) >> 21], 1u);
        atomicAdd(&hist[toSortable(v.y) >> 21], 1u);
        atomicAdd(&hist[toSortable(v.z) >> 21], 1u);
        atomicAdd(&hist[toSortable(v.w) >> 21], 1u);
    }
    __syncthreads();
    if (tid < 64) {
        unsigned running = 0;
        for (int c = NBINS / 64 - 1; c >= 0; --c) {
            int bin = c * 64 + tid;
            unsigned bc = hist[bin];
            unsigned incl = bc;
            #pragma unroll
            for (int d = 1; d < 64; d <<= 1) {
                unsigned o = __shfl_up(incl, d, 64);
                if (tid >= d) incl += o;
            }
            unsigned total = __shfl(incl, 63, 64);
            unsigned gt = running + (total - incl);
            bool cond = (gt < KSEL) && (gt + bc >= KSEL);
            unsigned long long msk = __ballot(cond);
            if (msk != 0ULL) {
                if (cond) { sh_b1 = bin; sh_g = (int)gt; }
                break;
            }
            running += total;
        }
    }
    __syncthreads();
    const int b1 = sh_b1;
    const int g  = sh_g;
    for (int j = 0; j < N_COLS / 4 / TPB; ++j) {
        int f = j * TPB + tid;
        float4 v = xr[f];
        #define FPROC2(comp, e)                                                   \
        {                                                                         \
            unsigned s = toSortable(v.comp);                                      \
            int b = (int)(s >> 21);                                               \
            if (b > b1) {                                                         \
                out[(size_t)row * N_COLS + f * 4 + e] = fmaxf(v.comp, 0.0f);      \
            } else if (b == b1) {                                                 \
                int p = atomicAdd(&sh_c, 1);                                      \
                if (p < CAPF) {                                                   \
                    lc[p] = ((unsigned long long)s << 15) |                       \
                            (unsigned long long)(24575 - (f * 4 + e));            \
                }                                                                 \
            }                                                                     \
        }
        FPROC2(x, 0) FPROC2(y, 1) FPROC2(z, 2) FPROC2(w, 3)
        #undef FPROC2
    }
    __syncthreads();
    int C2 = sh_c < CAPF ? sh_c : CAPF;
    const int k1 = KSEL - g;
    for (int i = tid; i < C2; i += TPB) {
        unsigned long long ki = lc[i];
        int rank = 0;
        for (int j = 0; j < C2; ++j)
            rank += (lc[j] > ki) ? 1 : 0;
        if (rank < k1) {
            int idx = 24575 - (int)(ki & 0x7FFFULL);
            float v = fromSortable((unsigned)(ki >> 15));
            out[(size_t)row * N_COLS + idx] = fmaxf(v, 0.0f);
        }
    }
}

extern "C" void kernel_launch(void* const* d_in, const int* in_sizes, int n_in,
                              void* d_out, int out_size, void* d_ws, size_t ws_size,
                              hipStream_t stream) {
    const float* x = (const float*)d_in[0];
    float* out = (float*)d_out;

    if (ws_size >= WS_NEED) {
        unsigned* hdr = (unsigned*)d_ws;   // {total, flag, cnt2[4096]}
        unsigned long long* gcand = (unsigned long long*)((char*)d_ws + GCAND_OFF);
        unsigned long long* rowcand = gcand + GCAP;
        zero_hdr_kernel<<<(ROWS + 2 + TPB - 1) / TPB, TPB, 0, stream>>>(hdr);
        collect_kernel<<<GRID1, TPB, 0, stream>>>(x, hdr, gcand);
        fill_zero_kernel<<<GRID1, TPB, 0, stream>>>((float4*)out);
        bin_kernel<<<512, TPB, 0, stream>>>(hdr, gcand, rowcand);
        select_scatter_kernel<<<ROWS, TPB, 0, stream>>>(x, hdr, rowcand, out);
    } else {
        fused_topk_kernel<<<ROWS, TPB, 0, stream>>>(x, out);
    }
}

// Round 9
// 168.591 us; speedup vs baseline: 2.0641x; 1.6821x over previous
//
#include <hip/hip_runtime.h>

#define N_COLS 24576
#define ROWS 4096
#define KSEL 64
#define TPB 256
#define PRE_F 2.5f      // static prefilter; 64th-largest of a N(0,1) row ≈ 2.79±0.04
#define CAPF 512        // per-row candidate cap (E≈152, σ≈12.3 → 29σ margin)
#define NBINS 2048
#define WAVE_F4 384     // float4 per wave slice (4 waves × 384 = 1536 = row)
#define LANE_F4 6       // float4 per lane (384/64)

__device__ __forceinline__ unsigned toSortable(float x) {
    unsigned u = __float_as_uint(x);
    return (u & 0x80000000u) ? ~u : (u | 0x80000000u);
}
__device__ __forceinline__ float fromSortable(unsigned s) {
    unsigned u = (s & 0x80000000u) ? (s & 0x7FFFFFFFu) : ~s;
    return __uint_as_float(u);
}

extern "C" __global__ void __launch_bounds__(TPB, 8)
topk_relu_kernel(const float* __restrict__ x, float* __restrict__ out) {
    __shared__ unsigned long long lc[CAPF];    // 4 KB
    __shared__ unsigned hist[NBINS];           // 8 KB (fallback only)
    __shared__ int sh_c, sh_b1, sh_g;

    const int tid  = threadIdx.x;
    const int lane = tid & 63;
    const int wave = tid >> 6;
    const int row  = blockIdx.x;
    const float4* __restrict__ xr = (const float4*)(x + (size_t)row * N_COLS);
    float4* __restrict__ outr     = (float4*)(out + (size_t)row * N_COLS);
    const int base_f4 = wave * WAVE_F4;        // this wave's slice (read AND write)

    if (tid == 0) sh_c = 0;
    __syncthreads();

    const float4 z4 = {0.0f, 0.0f, 0.0f, 0.0f};

    // ---- phase-staggered streaming: even waves W->R, odd waves R->W ----
    auto do_write = [&]() {
        #pragma unroll
        for (int k = 0; k < LANE_F4; ++k)
            outr[base_f4 + k * 64 + lane] = z4;
    };
    auto do_read = [&]() {
        float4 v[LANE_F4];
        #pragma unroll
        for (int k = 0; k < LANE_F4; ++k)           // 6 back-to-back dwordx4 loads
            v[k] = xr[base_f4 + k * 64 + lane];
        #pragma unroll
        for (int k = 0; k < LANE_F4; ++k) {
            if (fmaxf(fmaxf(v[k].x, v[k].y), fmaxf(v[k].z, v[k].w)) > PRE_F) {
                int fb = (base_f4 + k * 64 + lane) * 4;
                float vv[4] = {v[k].x, v[k].y, v[k].z, v[k].w};
                #pragma unroll
                for (int e = 0; e < 4; ++e) {
                    if (vv[e] > PRE_F) {
                        int p = atomicAdd(&sh_c, 1);
                        if (p < CAPF)
                            lc[p] = ((unsigned long long)toSortable(vv[e]) << 15)
                                  | (unsigned long long)(24575 - (fb + e));
                    }
                }
            }
        }
    };

    if (wave & 1) { do_read(); do_write(); }
    else          { do_write(); do_read(); }

    __syncthreads();   // drains all waves' zero stores (vmcnt) + lc complete

    int C = sh_c;
    if (C >= KSEL && C <= CAPF) {
        // ---- fast exact path: rank-select top-64 among candidates ----
        // Everything excluded by the prefilter is < every candidate, so top-64
        // of candidates == top-64 of the row. Raw u64 compare implements
        // (value desc, index asc) — jax.lax.top_k's tie-break.
        for (int i = tid; i < C; i += TPB) {
            unsigned long long ki = lc[i];
            int rank = 0;
            for (int j = 0; j < C; ++j)
                rank += (lc[j] > ki) ? 1 : 0;      // broadcast LDS reads
            if (rank < KSEL) {
                int idx = 24575 - (int)(ki & 0x7FFFULL);
                float v = fromSortable((unsigned)(ki >> 15));
                out[(size_t)row * N_COLS + idx] = fmaxf(v, 0.0f);
            }
        }
        return;
    }

    // ---- exact histogram fallback (not taken for N(0,1) input, always correct) ----
    for (int i = tid; i < NBINS; i += TPB) hist[i] = 0u;
    if (tid == 0) sh_c = 0;
    __syncthreads();

    for (int j = 0; j < N_COLS / 4 / TPB; ++j) {
        int f = j * TPB + tid;
        float4 v = xr[f];
        atomicAdd(&hist[toSortable(v.x) >> 21], 1u);
        atomicAdd(&hist[toSortable(v.y) >> 21], 1u);
        atomicAdd(&hist[toSortable(v.z) >> 21], 1u);
        atomicAdd(&hist[toSortable(v.w) >> 21], 1u);
    }
    __syncthreads();

    if (tid < 64) {
        unsigned running = 0;
        for (int c = NBINS / 64 - 1; c >= 0; --c) {
            int bin = c * 64 + tid;
            unsigned bc = hist[bin];
            unsigned incl = bc;
            #pragma unroll
            for (int d = 1; d < 64; d <<= 1) {
                unsigned o = __shfl_up(incl, d, 64);
                if (tid >= d) incl += o;
            }
            unsigned total = __shfl(incl, 63, 64);
            unsigned gt = running + (total - incl);
            bool cond = (gt < KSEL) && (gt + bc >= KSEL);
            unsigned long long msk = __ballot(cond);
            if (msk != 0ULL) {
                if (cond) { sh_b1 = bin; sh_g = (int)gt; }
                break;
            }
            running += total;
        }
    }
    __syncthreads();

    const int b1 = sh_b1;
    const int g  = sh_g;

    for (int j = 0; j < N_COLS / 4 / TPB; ++j) {
        int f = j * TPB + tid;
        float4 v = xr[f];
        #define FPROC(comp, e)                                                    \
        {                                                                         \
            unsigned s = toSortable(v.comp);                                      \
            int b = (int)(s >> 21);                                               \
            if (b > b1) {                                                         \
                out[(size_t)row * N_COLS + f * 4 + e] = fmaxf(v.comp, 0.0f);      \
            } else if (b == b1) {                                                 \
                int p = atomicAdd(&sh_c, 1);                                      \
                if (p < CAPF) {                                                   \
                    lc[p] = ((unsigned long long)s << 15) |                       \
                            (unsigned long long)(24575 - (f * 4 + e));            \
                }                                                                 \
            }                                                                     \
        }
        FPROC(x, 0) FPROC(y, 1) FPROC(z, 2) FPROC(w, 3)
        #undef FPROC
    }
    __syncthreads();

    int C2 = sh_c < CAPF ? sh_c : CAPF;
    const int k1 = KSEL - g;
    for (int i = tid; i < C2; i += TPB) {
        unsigned long long ki = lc[i];
        int rank = 0;
        for (int j = 0; j < C2; ++j)
            rank += (lc[j] > ki) ? 1 : 0;
        if (rank < k1) {
            int idx = 24575 - (int)(ki & 0x7FFFULL);
            float v = fromSortable((unsigned)(ki >> 15));
            out[(size_t)row * N_COLS + idx] = fmaxf(v, 0.0f);
        }
    }
}

extern "C" void kernel_launch(void* const* d_in, const int* in_sizes, int n_in,
                              void* d_out, int out_size, void* d_ws, size_t ws_size,
                              hipStream_t stream) {
    const float* x = (const float*)d_in[0];
    float* out = (float*)d_out;
    const int rows = in_sizes[0] / N_COLS;
    topk_relu_kernel<<<rows, TPB, 0, stream>>>(x, out);
}